// Round 12
// baseline (451.913 us; speedup 1.0000x reference)
//
#include <hip/hip_runtime.h>
#include <hip/hip_bf16.h>
#include <math.h>

// Problem constants
#define N_NODES 30
#define E_BASE  82
#define E_TOT   112         // 82 edges + 30 self loops
#define B_GRAPH 1024
#define HID     256
#define NTOT    (B_GRAPH * N_NODES)   // 30720
#define MAXIN   32
#define N_EH    41
#define M_MLP   (B_GRAPH * N_EH)      // 41984

#define META_SRC  0
#define META_DST  E_TOT
#define META_CNT  (2 * E_TOT)
#define META_LIST 256
#define META_INTS 1216

typedef __attribute__((ext_vector_type(8))) short bf16x8;
typedef __attribute__((ext_vector_type(4))) short bf16x4;
typedef __attribute__((ext_vector_type(4))) float f32x4;
#define AS3 __attribute__((address_space(3)))
#define AS1 __attribute__((address_space(1)))

__device__ __forceinline__ void gload_lds16(const void* g, void* l) {
  __builtin_amdgcn_global_load_lds((const AS1 void*)g, (AS3 void*)l, 16, 0, 0);
}

// Bit-reinterpret ONLY — callers must pass raw bf16 bit patterns (short lanes
// of bf16x4/8 vectors). Never pass __hip_bfloat16 (would value-convert via
// float->short — the R3 NaN bug).
__device__ __forceinline__ float b2f(short s) {
  union { unsigned u; float f; } x;
  x.u = ((unsigned)(unsigned short)s) << 16;
  return x.f;
}

// ---------------------------------------------------------------------------
// Transpose-cast all weights fp32 [K,N] -> bf16 [N,K]; block 976 instead
// builds the base-graph CSR (merged to save a launch).
// ---------------------------------------------------------------------------
struct WtJob { const float* in; int K, N, tstart, ooff; };
struct WtArgs { WtJob j[10]; };

__global__ __launch_bounds__(256)
void transpose_weights(WtArgs args, __hip_bfloat16* __restrict__ out,
                       const int* __restrict__ ei, int* __restrict__ meta) {
  int b = blockIdx.x;
  if (b == 976) {   // build_graph job
    __shared__ int cnt[N_NODES];
    int tid = threadIdx.x;
    if (tid < N_NODES) cnt[tid] = 0;
    __syncthreads();
    if (tid < E_TOT) {
      int s, d;
      if (tid < E_BASE) { s = ei[tid]; d = ei[B_GRAPH * E_BASE + tid]; }
      else              { s = tid - E_BASE; d = s; }
      meta[META_SRC + tid] = s;
      meta[META_DST + tid] = d;
      int pos = atomicAdd(&cnt[d], 1);
      if (pos < MAXIN) meta[META_LIST + d * MAXIN + pos] = tid;
    }
    __syncthreads();
    if (tid < N_NODES) meta[META_CNT + tid] = cnt[tid];
    return;
  }
  int ji = 0;
  #pragma unroll
  for (int i = 1; i < 10; i++) if (b >= args.j[i].tstart) ji = i;
  WtJob jb = args.j[ji];
  int t = b - jb.tstart;
  int ntn = jb.N >> 5;
  int tk = t / ntn, tn = t - tk * ntn;
  int k0 = tk * 32, n0 = tn * 32;
  __shared__ float s[32][33];
  int tx = threadIdx.x & 31, ty = threadIdx.x >> 5;
  #pragma unroll
  for (int p = 0; p < 4; p++)
    s[ty + p * 8][tx] = jb.in[(size_t)(k0 + ty + p * 8) * jb.N + n0 + tx];
  __syncthreads();
  __hip_bfloat16* o = out + jb.ooff;
  #pragma unroll
  for (int p = 0; p < 4; p++) {
    int n = ty + p * 8;
    o[(size_t)(n0 + n) * jb.K + k0 + tx] = __float2bfloat16(s[tx][n]);
  }
}

// ---------------------------------------------------------------------------
// bf16 MFMA GEMM (R9 fragment/epilogue config; BK=64: two [128][32] sub-tiles
// staged per barrier pair — halves barrier-drain count, bank layout unchanged).
// C = act(A @ B + bias); A [M,K] bf16, Bt [N,K] bf16. K % 64 == 0.
// Split bias: col < N1 -> bias[col], else bias2[col-N1] (concat outputs).
// ---------------------------------------------------------------------------
template<int ACT, int OUTBF>
__global__ __launch_bounds__(256)
void gemm_mfma(const __hip_bfloat16* __restrict__ A, const __hip_bfloat16* __restrict__ Bt,
               const float* __restrict__ bias, const float* __restrict__ bias2,
               void* __restrict__ Cv, int M, int K, int N, int N1)
{
  __shared__ __hip_bfloat16 sA[2][128 * 32];
  __shared__ __hip_bfloat16 sB[2][128 * 32];
  const int tid = threadIdx.x;
  const int lane = tid & 63;
  const int wave = tid >> 6;
  const int wx = wave & 1, wy = wave >> 1;
  const int bm = blockIdx.x, bn = blockIdx.y;
  const int mrow = lane & 15, quad = lane >> 4;

  const int r0 = tid >> 2, kc0 = (tid & 3) * 8;
  const __hip_bfloat16* Ag0 = A + (size_t)(bm * 128 + r0) * K + kc0;
  const __hip_bfloat16* Ag1 = A + (size_t)(bm * 128 + r0 + 64) * K + kc0;
  const __hip_bfloat16* Bg0 = Bt + (size_t)(bn * 128 + r0) * K + kc0;
  const __hip_bfloat16* Bg1 = Bt + (size_t)(bn * 128 + r0 + 64) * K + kc0;

  f32x4 acc[4][4];
  #pragma unroll
  for (int i = 0; i < 4; i++)
    #pragma unroll
    for (int j = 0; j < 4; j++)
      acc[i][j] = (f32x4){0.f, 0.f, 0.f, 0.f};

  for (int kt = 0; kt < K; kt += 64) {
    __syncthreads();
    #pragma unroll
    for (int s = 0; s < 2; s++) {
      gload_lds16(Ag0 + kt + s * 32, &sA[s][tid * 8]);
      gload_lds16(Ag1 + kt + s * 32, &sA[s][2048 + tid * 8]);
      gload_lds16(Bg0 + kt + s * 32, &sB[s][tid * 8]);
      gload_lds16(Bg1 + kt + s * 32, &sB[s][2048 + tid * 8]);
    }
    __syncthreads();

    #pragma unroll
    for (int s = 0; s < 2; s++) {
      bf16x8 af[4], bfr[4];
      #pragma unroll
      for (int i = 0; i < 4; i++) {
        af[i]  = *(const bf16x8*)&sA[s][(wy * 64 + i * 16 + mrow) * 32 + quad * 8];
        bfr[i] = *(const bf16x8*)&sB[s][(wx * 64 + i * 16 + mrow) * 32 + quad * 8];
      }
      #pragma unroll
      for (int i = 0; i < 4; i++)
        #pragma unroll
        for (int j = 0; j < 4; j++)
          acc[i][j] = __builtin_amdgcn_mfma_f32_16x16x32_bf16(af[i], bfr[j], acc[i][j], 0, 0, 0);
    }
  }

  #pragma unroll
  for (int i = 0; i < 4; i++) {
    #pragma unroll
    for (int r = 0; r < 4; r++) {
      size_t row = (size_t)bm * 128 + wy * 64 + i * 16 + quad * 4 + r;
      #pragma unroll
      for (int j = 0; j < 4; j++) {
        int col = bn * 128 + wx * 64 + j * 16 + mrow;
        float bc = (col < N1) ? bias[col] : bias2[col - N1];
        float v = acc[i][j][r] + bc;
        if (ACT) v = v > 0.f ? v : 0.01f * v;
        if (OUTBF) ((__hip_bfloat16*)Cv)[row * N + col] = __float2bfloat16(v);
        else       ((float*)Cv)[row * N + col] = v;
      }
    }
  }
}

// ---------------------------------------------------------------------------
// MFMA GEMM with fp32 A staged via in-register bf16 cast (fused cast): proj.
// (Unchanged R9 config — not the bottleneck.)
// ---------------------------------------------------------------------------
template<int ACT, int OUTBF>
__global__ __launch_bounds__(256)
void gemm_mfma_f32a(const float* __restrict__ A, const __hip_bfloat16* __restrict__ Bt,
                    const float* __restrict__ bias, void* __restrict__ Cv,
                    int M, int K, int N)
{
  __shared__ __hip_bfloat16 sA[128 * 32];
  __shared__ __hip_bfloat16 sB[128 * 32];
  const int tid = threadIdx.x;
  const int lane = tid & 63;
  const int wave = tid >> 6;
  const int wx = wave & 1, wy = wave >> 1;
  const int bm = blockIdx.x, bn = blockIdx.y;
  const int mrow = lane & 15, quad = lane >> 4;

  const int r0 = tid >> 2, kc0 = (tid & 3) * 8;
  const float* Ag0 = A + (size_t)(bm * 128 + r0) * K + kc0;
  const float* Ag1 = A + (size_t)(bm * 128 + r0 + 64) * K + kc0;
  const __hip_bfloat16* Bg0 = Bt + (size_t)(bn * 128 + r0) * K + kc0;
  const __hip_bfloat16* Bg1 = Bt + (size_t)(bn * 128 + r0 + 64) * K + kc0;

  f32x4 acc[4][4];
  #pragma unroll
  for (int i = 0; i < 4; i++)
    #pragma unroll
    for (int j = 0; j < 4; j++)
      acc[i][j] = (f32x4){0.f, 0.f, 0.f, 0.f};

  for (int kt = 0; kt < K; kt += 32) {
    float4 a00 = *(const float4*)(Ag0 + kt);
    float4 a01 = *(const float4*)(Ag0 + kt + 4);
    float4 a10 = *(const float4*)(Ag1 + kt);
    float4 a11 = *(const float4*)(Ag1 + kt + 4);
    __syncthreads();
    {
      __hip_bfloat16 t[8];
      t[0] = __float2bfloat16(a00.x); t[1] = __float2bfloat16(a00.y);
      t[2] = __float2bfloat16(a00.z); t[3] = __float2bfloat16(a00.w);
      t[4] = __float2bfloat16(a01.x); t[5] = __float2bfloat16(a01.y);
      t[6] = __float2bfloat16(a01.z); t[7] = __float2bfloat16(a01.w);
      *(bf16x8*)&sA[tid * 8] = *(bf16x8*)t;
      t[0] = __float2bfloat16(a10.x); t[1] = __float2bfloat16(a10.y);
      t[2] = __float2bfloat16(a10.z); t[3] = __float2bfloat16(a10.w);
      t[4] = __float2bfloat16(a11.x); t[5] = __float2bfloat16(a11.y);
      t[6] = __float2bfloat16(a11.z); t[7] = __float2bfloat16(a11.w);
      *(bf16x8*)&sA[2048 + tid * 8] = *(bf16x8*)t;
    }
    gload_lds16(Bg0 + kt, &sB[tid * 8]);
    gload_lds16(Bg1 + kt, &sB[2048 + tid * 8]);
    __syncthreads();

    bf16x8 af[4], bfr[4];
    #pragma unroll
    for (int i = 0; i < 4; i++) {
      af[i]  = *(const bf16x8*)&sA[(wy * 64 + i * 16 + mrow) * 32 + quad * 8];
      bfr[i] = *(const bf16x8*)&sB[(wx * 64 + i * 16 + mrow) * 32 + quad * 8];
    }
    #pragma unroll
    for (int i = 0; i < 4; i++)
      #pragma unroll
      for (int j = 0; j < 4; j++)
        acc[i][j] = __builtin_amdgcn_mfma_f32_16x16x32_bf16(af[i], bfr[j], acc[i][j], 0, 0, 0);
  }

  #pragma unroll
  for (int i = 0; i < 4; i++) {
    #pragma unroll
    for (int r = 0; r < 4; r++) {
      size_t row = (size_t)bm * 128 + wy * 64 + i * 16 + quad * 4 + r;
      #pragma unroll
      for (int j = 0; j < 4; j++) {
        int col = bn * 128 + wx * 64 + j * 16 + mrow;
        float v = acc[i][j][r] + bias[col];
        if (ACT) v = v > 0.f ? v : 0.01f * v;
        if (OUTBF) ((__hip_bfloat16*)Cv)[row * N + col] = __float2bfloat16(v);
        else       ((float*)Cv)[row * N + col] = v;
      }
    }
  }
}

// ---------------------------------------------------------------------------
// MFMA GEMM with fused edge-pair gather from fp32 h:
// A-row r = concat(h[b,u], h[b,v]) with b=r/41, (u,v)=pairs[r%41]; K=512.
// C = lrelu(A @ Bt + bias), bf16 out. (Unchanged R9 config.)
// ---------------------------------------------------------------------------
__global__ __launch_bounds__(256)
void gemm_mfma_pair(const float* __restrict__ h, const int* __restrict__ pairs,
                    const __hip_bfloat16* __restrict__ Bt, const float* __restrict__ bias,
                    __hip_bfloat16* __restrict__ C, int N)
{
  const int K = 512;
  __shared__ __hip_bfloat16 sA[128 * 32];
  __shared__ __hip_bfloat16 sB[128 * 32];
  const int tid = threadIdx.x;
  const int lane = tid & 63;
  const int wave = tid >> 6;
  const int wx = wave & 1, wy = wave >> 1;
  const int bm = blockIdx.x, bn = blockIdx.y;
  const int mrow = lane & 15, quad = lane >> 4;

  const float* pu[2]; const float* pv[2]; int sub[2];
  #pragma unroll
  for (int cI = 0; cI < 2; cI++) {
    int c = tid + cI * 256;
    int r0 = c >> 2; sub[cI] = (c & 3) * 8;
    int R = bm * 128 + r0;
    int b = R / N_EH, p = R - b * N_EH;
    int u = pairs[p * 2], v = pairs[p * 2 + 1];
    pu[cI] = h + ((size_t)b * N_NODES + u) * HID;
    pv[cI] = h + ((size_t)b * N_NODES + v) * HID;
  }

  const int r0 = tid >> 2, kc0 = (tid & 3) * 8;
  const __hip_bfloat16* Bg0 = Bt + (size_t)(bn * 128 + r0) * K + kc0;
  const __hip_bfloat16* Bg1 = Bt + (size_t)(bn * 128 + r0 + 64) * K + kc0;

  f32x4 acc[4][4];
  #pragma unroll
  for (int i = 0; i < 4; i++)
    #pragma unroll
    for (int j = 0; j < 4; j++)
      acc[i][j] = (f32x4){0.f, 0.f, 0.f, 0.f};

  for (int kt = 0; kt < K; kt += 32) {
    float4 av[2][2];
    #pragma unroll
    for (int cI = 0; cI < 2; cI++) {
      const float* src = (kt < 256 ? pu[cI] + kt : pv[cI] + kt - 256) + sub[cI];
      av[cI][0] = *(const float4*)src;
      av[cI][1] = *(const float4*)(src + 4);
    }
    __syncthreads();
    #pragma unroll
    for (int cI = 0; cI < 2; cI++) {
      __hip_bfloat16 t[8];
      t[0] = __float2bfloat16(av[cI][0].x); t[1] = __float2bfloat16(av[cI][0].y);
      t[2] = __float2bfloat16(av[cI][0].z); t[3] = __float2bfloat16(av[cI][0].w);
      t[4] = __float2bfloat16(av[cI][1].x); t[5] = __float2bfloat16(av[cI][1].y);
      t[6] = __float2bfloat16(av[cI][1].z); t[7] = __float2bfloat16(av[cI][1].w);
      *(bf16x8*)&sA[(tid + cI * 256) * 8] = *(bf16x8*)t;
    }
    gload_lds16(Bg0 + kt, &sB[tid * 8]);
    gload_lds16(Bg1 + kt, &sB[2048 + tid * 8]);
    __syncthreads();

    bf16x8 af[4], bfr[4];
    #pragma unroll
    for (int i = 0; i < 4; i++) {
      af[i]  = *(const bf16x8*)&sA[(wy * 64 + i * 16 + mrow) * 32 + quad * 8];
      bfr[i] = *(const bf16x8*)&sB[(wx * 64 + i * 16 + mrow) * 32 + quad * 8];
    }
    #pragma unroll
    for (int i = 0; i < 4; i++)
      #pragma unroll
      for (int j = 0; j < 4; j++)
        acc[i][j] = __builtin_amdgcn_mfma_f32_16x16x32_bf16(af[i], bfr[j], acc[i][j], 0, 0, 0);
  }

  #pragma unroll
  for (int i = 0; i < 4; i++) {
    #pragma unroll
    for (int r = 0; r < 4; r++) {
      size_t row = (size_t)bm * 128 + wy * 64 + i * 16 + quad * 4 + r;
      #pragma unroll
      for (int j = 0; j < 4; j++) {
        int col = bn * 128 + wx * 64 + j * 16 + mrow;
        float v = acc[i][j][r] + bias[col];
        v = v > 0.f ? v : 0.01f * v;
        C[row * N + col] = __float2bfloat16(v);
      }
    }
  }
}

// ---------------------------------------------------------------------------
// Fused MLP tail (unchanged from R11 — proven win).
// ---------------------------------------------------------------------------
#define O2P 136
__global__ __launch_bounds__(256)
void mlp_tail(const __hip_bfloat16* __restrict__ o1, const __hip_bfloat16* __restrict__ W1t,
              const float* __restrict__ b1, const __hip_bfloat16* __restrict__ W2t,
              const float* __restrict__ b2, const float* __restrict__ w3,
              const float* __restrict__ b3, float* __restrict__ out)
{
  __shared__ __hip_bfloat16 sA[128 * 32];
  __shared__ __hip_bfloat16 sB[128 * 32];
  __shared__ __hip_bfloat16 sO2[128 * O2P];
  __shared__ float spart[2][128];
  const int tid = threadIdx.x;
  const int lane = tid & 63;
  const int wave = tid >> 6;
  const int wx = wave & 1, wy = wave >> 1;
  const int bm = blockIdx.x;
  const int mrow = lane & 15, quad = lane >> 4;
  const int r0 = tid >> 2, kc0 = (tid & 3) * 8;

  const __hip_bfloat16* Ag0 = o1 + (size_t)(bm * 128 + r0) * 256 + kc0;
  const __hip_bfloat16* Ag1 = o1 + (size_t)(bm * 128 + r0 + 64) * 256 + kc0;
  const __hip_bfloat16* Bg0 = W1t + (size_t)r0 * 256 + kc0;
  const __hip_bfloat16* Bg1 = W1t + (size_t)(r0 + 64) * 256 + kc0;

  f32x4 acc[4][4];
  #pragma unroll
  for (int i = 0; i < 4; i++)
    #pragma unroll
    for (int j = 0; j < 4; j++)
      acc[i][j] = (f32x4){0.f, 0.f, 0.f, 0.f};

  for (int kt = 0; kt < 256; kt += 32) {
    __syncthreads();
    gload_lds16(Ag0 + kt, &sA[tid * 8]);
    gload_lds16(Ag1 + kt, &sA[2048 + tid * 8]);
    gload_lds16(Bg0 + kt, &sB[tid * 8]);
    gload_lds16(Bg1 + kt, &sB[2048 + tid * 8]);
    __syncthreads();

    bf16x8 af[4], bfr[4];
    #pragma unroll
    for (int i = 0; i < 4; i++) {
      af[i]  = *(const bf16x8*)&sA[(wy * 64 + i * 16 + mrow) * 32 + quad * 8];
      bfr[i] = *(const bf16x8*)&sB[(wx * 64 + i * 16 + mrow) * 32 + quad * 8];
    }
    #pragma unroll
    for (int i = 0; i < 4; i++)
      #pragma unroll
      for (int j = 0; j < 4; j++)
        acc[i][j] = __builtin_amdgcn_mfma_f32_16x16x32_bf16(af[i], bfr[j], acc[i][j], 0, 0, 0);
  }

  __syncthreads();
  #pragma unroll
  for (int i = 0; i < 4; i++) {
    #pragma unroll
    for (int r = 0; r < 4; r++) {
      int row = wy * 64 + i * 16 + quad * 4 + r;
      #pragma unroll
      for (int j = 0; j < 4; j++) {
        int col = wx * 64 + j * 16 + mrow;
        float v = acc[i][j][r] + b1[col];
        v = v > 0.f ? v : 0.01f * v;
        sO2[row * O2P + col] = __float2bfloat16(v);
      }
    }
  }

  f32x4 acc2[4][4];
  #pragma unroll
  for (int i = 0; i < 4; i++)
    #pragma unroll
    for (int j = 0; j < 4; j++)
      acc2[i][j] = (f32x4){0.f, 0.f, 0.f, 0.f};

  for (int kt = 0; kt < 128; kt += 32) {
    __syncthreads();
    gload_lds16(W2t + (size_t)r0 * 128 + kt + kc0, &sB[tid * 8]);
    gload_lds16(W2t + (size_t)(r0 + 64) * 128 + kt + kc0, &sB[2048 + tid * 8]);
    __syncthreads();

    bf16x8 af[4], bfr[4];
    #pragma unroll
    for (int i = 0; i < 4; i++) {
      af[i]  = *(const bf16x8*)&sO2[(wy * 64 + i * 16 + mrow) * O2P + kt + quad * 8];
      bfr[i] = *(const bf16x8*)&sB[(wx * 64 + i * 16 + mrow) * 32 + quad * 8];
    }
    #pragma unroll
    for (int i = 0; i < 4; i++)
      #pragma unroll
      for (int j = 0; j < 4; j++)
        acc2[i][j] = __builtin_amdgcn_mfma_f32_16x16x32_bf16(af[i], bfr[j], acc2[i][j], 0, 0, 0);
  }

  float w3v[4], b2v[4];
  #pragma unroll
  for (int j = 0; j < 4; j++) {
    int col = wx * 64 + j * 16 + mrow;
    w3v[j] = w3[col];
    b2v[j] = b2[col];
  }
  #pragma unroll
  for (int i = 0; i < 4; i++) {
    #pragma unroll
    for (int r = 0; r < 4; r++) {
      float s = 0.f;
      #pragma unroll
      for (int j = 0; j < 4; j++) {
        float v = acc2[i][j][r] + b2v[j];
        v = v > 0.f ? v : 0.01f * v;
        s += v * w3v[j];
      }
      #pragma unroll
      for (int off = 8; off; off >>= 1) s += __shfl_xor(s, off);
      if (mrow == 0) {
        int row = wy * 64 + i * 16 + quad * 4 + r;
        spart[wx][row] = s;
      }
    }
  }
  __syncthreads();
  if (tid < 128)
    out[(size_t)bm * 128 + tid] = spart[0][tid] + spart[1][tid] + b3[0];
}

// ---------------------------------------------------------------------------
// LayerNorm over HID=256; one wave per row; writes bf16.
// ---------------------------------------------------------------------------
__global__ __launch_bounds__(256)
void layernorm(const float* __restrict__ h, const float* __restrict__ g,
               const float* __restrict__ b, __hip_bfloat16* __restrict__ hn)
{
  const int wv = threadIdx.x >> 6, lane = threadIdx.x & 63;
  const size_t row = (size_t)blockIdx.x * 4 + wv;
  const float* hr = h + row * HID;
  float v[4];
  float sum = 0.f;
  #pragma unroll
  for (int j = 0; j < 4; j++) { v[j] = hr[lane + 64 * j]; sum += v[j]; }
  #pragma unroll
  for (int off = 32; off; off >>= 1) sum += __shfl_xor(sum, off);
  float mu = sum * (1.f / 256.f);
  float vs = 0.f;
  #pragma unroll
  for (int j = 0; j < 4; j++) { float d = v[j] - mu; vs += d * d; }
  #pragma unroll
  for (int off = 32; off; off >>= 1) vs += __shfl_xor(vs, off);
  float rs = rsqrtf(vs * (1.f / 256.f) + 1e-5f);
  __hip_bfloat16* outr = hn + row * HID;
  #pragma unroll
  for (int j = 0; j < 4; j++) {
    int c = lane + 64 * j;
    outr[c] = __float2bfloat16((v[j] - mu) * rs * g[c] + b[c]);
  }
}

// ---------------------------------------------------------------------------
// GATv2 attention coefficients: one block per (graph, head). (Unchanged R9.)
// ---------------------------------------------------------------------------
__global__ __launch_bounds__(256)
void gat_alpha(const __hip_bfloat16* __restrict__ xcat,
               const float* __restrict__ att, float* __restrict__ alphaG,
               const int* __restrict__ meta, int H)
{
  __shared__ __hip_bfloat16 sxl[N_NODES * HID];   // 15 KB
  __shared__ __hip_bfloat16 sxr[N_NODES * HID];   // 15 KB
  __shared__ float slog[E_TOT];
  __shared__ float smax[N_NODES];
  __shared__ float sden[N_NODES];
  __shared__ int ssrc[E_TOT], sdst[E_TOT], scnt[N_NODES], slist[N_NODES * MAXIN];

  const int tid = threadIdx.x;
  const int g = blockIdx.x, hh = blockIdx.y;
  const size_t nodebase = (size_t)g * N_NODES;
  const int S = 2 * H * HID;

  {
    int i = tid;
    #pragma unroll
    for (int p = 0; p < 4; p++, i += 256) {
      if (i < N_NODES * HID / 8) {
        int node = i >> 5, c = (i & 31) * 8;
        const __hip_bfloat16* row = &xcat[(nodebase + node) * S + c];
        gload_lds16(row + hh * HID, &sxl[(size_t)i * 8]);
        gload_lds16(row + (H + hh) * HID, &sxr[(size_t)i * 8]);
      }
    }
  }

  if (tid < E_TOT) { ssrc[tid] = meta[META_SRC + tid]; sdst[tid] = meta[META_DST + tid]; }
  if (tid < N_NODES) { scnt[tid] = meta[META_CNT + tid]; sden[tid] = 0.f; }
  for (int i = tid; i < N_NODES * MAXIN; i += 256) slist[i] = meta[META_LIST + i];

  const int wv = tid >> 6, l32 = tid & 31, esub = (tid >> 5) & 1;
  const int c0 = l32 * 8;
  float attr[8];
  #pragma unroll
  for (int j = 0; j < 8; j++) attr[j] = att[hh * HID + c0 + j];
  __syncthreads();

  #pragma unroll
  for (int pass = 0; pass < 14; pass++) {
    int e = pass * 8 + wv * 2 + esub;
    bf16x8 a = *(const bf16x8*)&sxl[ssrc[e] * HID + c0];
    bf16x8 b = *(const bf16x8*)&sxr[sdst[e] * HID + c0];
    float sum = 0.f;
    #pragma unroll
    for (int j = 0; j < 8; j++) {
      float v = b2f(a[j]) + b2f(b[j]);
      v = v > 0.f ? v : 0.2f * v;
      sum += v * attr[j];
    }
    #pragma unroll
    for (int off = 16; off; off >>= 1) sum += __shfl_xor(sum, off);
    if (l32 == 0) slog[e] = sum;
  }
  __syncthreads();

  if (tid < N_NODES) {
    int cnt = scnt[tid];
    const int* lst = &slist[tid * MAXIN];
    float m = -1e30f;
    for (int i = 0; i < cnt; i++) m = fmaxf(m, slog[lst[i]]);
    smax[tid] = m;
  }
  __syncthreads();
  if (tid < E_TOT) {
    float ex = expf(slog[tid] - smax[sdst[tid]]);
    slog[tid] = ex;
    atomicAdd(&sden[sdst[tid]], ex);
  }
  __syncthreads();
  if (tid < E_TOT)
    alphaG[((size_t)g * H + hh) * E_TOT + tid] = slog[tid] / sden[sdst[tid]];
}

// ---------------------------------------------------------------------------
// GATv2 aggregation + h update. CHANNEL-SPLIT: block = (graph, half hf);
// each block owns 128 channels -> sxl halves to 7.5 KB/buffer, VGPR ~50,
// grid 2048 -> 8 blocks/CU (was 4). LN un-fused (needs full rows).
// Thread = (channel-quad c4 in 0..31, node-group ng in 0..7).
// ---------------------------------------------------------------------------
__global__ __launch_bounds__(256, 8)
void gat_agg(const __hip_bfloat16* __restrict__ xcat, const float* __restrict__ alphaG,
             const float* __restrict__ bias, float* __restrict__ h,
             const int* __restrict__ meta, int H)
{
  __shared__ __hip_bfloat16 sxl[2][N_NODES * 128];   // 2 x 7.5 KB
  __shared__ float salpha[2][E_TOT];
  __shared__ int ssrc[E_TOT], scnt[N_NODES], slist[N_NODES * MAXIN];

  const int tid = threadIdx.x;
  const int g = blockIdx.x, hf = blockIdx.y;
  const size_t nodebase = (size_t)g * N_NODES;
  const int S = 2 * H * HID;
  const int coff = hf * 128;
  const int c4 = tid & 31;     // channels coff + 4*c4 .. +3
  const int ng = tid >> 5;     // nodes {ng, ng+8, ng+16, ng+24}
  const int NCHK = N_NODES * 128 / 8;   // 480 16B-chunks per head-half

  if (tid < E_TOT) ssrc[tid] = meta[META_SRC + tid];
  if (tid < N_NODES) scnt[tid] = meta[META_CNT + tid];
  for (int i = tid; i < N_NODES * MAXIN; i += 256) slist[i] = meta[META_LIST + i];

  float4 hres[4];
  #pragma unroll
  for (int ki = 0; ki < 4; ki++) {
    int k = ng + ki * 8;
    if (k < N_NODES) hres[ki] = *(const float4*)&h[(nodebase + k) * HID + coff + c4 * 4];
  }

  // stage head 0
  {
    int i = tid;
    #pragma unroll
    for (int p = 0; p < 2; p++, i += 256) {
      if (i < NCHK) {
        int node = i >> 4, c = (i & 15) * 8;
        gload_lds16(&xcat[(nodebase + node) * S + 0 * HID + coff + c], &sxl[0][(size_t)i * 8]);
      }
    }
    if (tid < E_TOT) salpha[0][tid] = alphaG[((size_t)g * H + 0) * E_TOT + tid];
  }

  float acc[4][4];
  #pragma unroll
  for (int ki = 0; ki < 4; ki++)
    #pragma unroll
    for (int j = 0; j < 4; j++) acc[ki][j] = 0.f;

  for (int hh = 0; hh < H; hh++) {
    const int buf = hh & 1;
    __syncthreads();
    if (hh + 1 < H) {
      const int nb = buf ^ 1;
      int i = tid;
      #pragma unroll
      for (int p = 0; p < 2; p++, i += 256) {
        if (i < NCHK) {
          int node = i >> 4, c = (i & 15) * 8;
          gload_lds16(&xcat[(nodebase + node) * S + (hh + 1) * HID + coff + c],
                      &sxl[nb][(size_t)i * 8]);
        }
      }
      if (tid < E_TOT) salpha[nb][tid] = alphaG[((size_t)g * H + hh + 1) * E_TOT + tid];
    }
    #pragma unroll
    for (int ki = 0; ki < 4; ki++) {
      int k = ng + ki * 8;
      if (k < N_NODES) {
        int cnt = scnt[k];
        const int* lst = &slist[k * MAXIN];
        for (int i = 0; i < cnt; i++) {
          int e = lst[i];                       // half-wave-uniform broadcast
          float al = salpha[buf][e];
          bf16x4 v = *(const bf16x4*)&sxl[buf][ssrc[e] * 128 + c4 * 4];
          acc[ki][0] += al * b2f(v[0]);
          acc[ki][1] += al * b2f(v[1]);
          acc[ki][2] += al * b2f(v[2]);
          acc[ki][3] += al * b2f(v[3]);
        }
      }
    }
  }

  const float invH = 1.f / (float)H;
  const float4 bs = *(const float4*)&bias[coff + c4 * 4];
  #pragma unroll
  for (int ki = 0; ki < 4; ki++) {
    int k = ng + ki * 8;
    if (k < N_NODES) {
      float o0 = acc[ki][0] * invH + bs.x; o0 = o0 > 0.f ? o0 : 0.01f * o0; o0 += hres[ki].x;
      float o1 = acc[ki][1] * invH + bs.y; o1 = o1 > 0.f ? o1 : 0.01f * o1; o1 += hres[ki].y;
      float o2 = acc[ki][2] * invH + bs.z; o2 = o2 > 0.f ? o2 : 0.01f * o2; o2 += hres[ki].z;
      float o3 = acc[ki][3] * invH + bs.w; o3 = o3 > 0.f ? o3 : 0.01f * o3; o3 += hres[ki].w;
      float4 o4 = {o0, o1, o2, o3};
      *(float4*)&h[(nodebase + k) * HID + coff + c4 * 4] = o4;
    }
  }
}

// ---------------------------------------------------------------------------
extern "C" void kernel_launch(void* const* d_in, const int* in_sizes, int n_in,
                              void* d_out, int out_size, void* d_ws, size_t ws_size,
                              hipStream_t stream) {
  const float* x     = (const float*)d_in[0];
  const int*   ei    = (const int*)d_in[1];
  const int*   pairs = (const int*)d_in[2];
  const float* bp    = (const float*)d_in[4];
  const float *lng[3], *lnb[3], *bl[3], *br[3], *att[3], *bias[3];
  const float *WlF[3], *WrF[3];
  for (int l = 0; l < 3; l++) {
    int base = 5 + l * 8;
    lng[l]  = (const float*)d_in[base + 0];
    lnb[l]  = (const float*)d_in[base + 1];
    WlF[l]  = (const float*)d_in[base + 2];
    bl[l]   = (const float*)d_in[base + 3];
    WrF[l]  = (const float*)d_in[base + 4];
    br[l]   = (const float*)d_in[base + 5];
    att[l]  = (const float*)d_in[base + 6];
    bias[l] = (const float*)d_in[base + 7];
  }
  const float* WmF[4] = {(const float*)d_in[29], (const float*)d_in[31],
                         (const float*)d_in[33], (const float*)d_in[35]};
  const float* bm[4] = {(const float*)d_in[30], (const float*)d_in[32],
                        (const float*)d_in[34], (const float*)d_in[36]};

  // workspace layout (float offsets)
  float* ws  = (float*)d_ws;
  float* h   = ws;                                           // [0, 7864320)
  __hip_bfloat16* hnb = (__hip_bfloat16*)(ws + 7864320);     // 3,932,160 bf
  __hip_bfloat16* xcat = (__hip_bfloat16*)(ws + 11796480);   // up to 47,185,920 bf
  float* alphaG = ws + 35389440;                             // 344,064 f
  __hip_bfloat16* wbuf = (__hip_bfloat16*)(ws + 35733504);   // 999,424 bf
  int*   meta = (int*)(ws + 36233216);
  __hip_bfloat16* o1b = (__hip_bfloat16*)xcat;               // 10,747,904 bf (xcat dead)
  float* out = (float*)d_out;

  // bf16 transposed weight offsets (Wl and Wr contiguous per layer -> one GEMM)
  const int oWp = 0, oWl0 = 32768, oWr0 = 229376, oWl1 = 425984, oWr1 = 557056;
  const int oWl2 = 688128, oWr2 = 753664, oWm0 = 819200, oWm1 = 950272, oWm2 = 983040;

  WtArgs wa;
  wa.j[0] = {(const float*)d_in[3], 128, 256,   0, oWp };
  wa.j[1] = {WlF[0],              256, 768,  32, oWl0};
  wa.j[2] = {WrF[0],              256, 768, 224, oWr0};
  wa.j[3] = {WlF[1],              256, 512, 416, oWl1};
  wa.j[4] = {WrF[1],              256, 512, 544, oWr1};
  wa.j[5] = {WlF[2],              256, 256, 672, oWl2};
  wa.j[6] = {WrF[2],              256, 256, 736, oWr2};
  wa.j[7] = {WmF[0],              512, 256, 800, oWm0};
  wa.j[8] = {WmF[1],              256, 128, 928, oWm1};
  wa.j[9] = {WmF[2],              128, 128, 960, oWm2};
  transpose_weights<<<977, 256, 0, stream>>>(wa, wbuf, ei, meta);  // block 976 = build_graph

  // h = x @ Wp + bp   (fp32 A staged with fused bf16 cast; fp32 out)
  gemm_mfma_f32a<0, 0><<<dim3(NTOT / 128, 2), 256, 0, stream>>>(x, wbuf + oWp, bp, h,
                                                                NTOT, 128, 256);

  layernorm<<<NTOT / 4, 256, 0, stream>>>(h, lng[0], lnb[0], hnb);

  const int Hs[3] = {3, 2, 1};
  const int oWl[3] = {oWl0, oWl1, oWl2};
  for (int l = 0; l < 3; l++) {
    int N = 2 * Hs[l] * HID;   // combined xl|xr output
    gemm_mfma<0, 1><<<dim3(NTOT / 128, N / 128), 256, 0, stream>>>(
        hnb, wbuf + oWl[l], bl[l], br[l], xcat, NTOT, HID, N, N / 2);
    gat_alpha<<<dim3(B_GRAPH, Hs[l]), 256, 0, stream>>>(xcat, att[l], alphaG, meta, Hs[l]);
    gat_agg<<<dim3(B_GRAPH, 2), 256, 0, stream>>>(xcat, alphaG, bias[l], h, meta, Hs[l]);
    if (l < 2)
      layernorm<<<NTOT / 4, 256, 0, stream>>>(h, lng[l + 1], lnb[l + 1], hnb);
  }

  gemm_mfma_pair<<<dim3(M_MLP / 128, 2), 256, 0, stream>>>(h, pairs, wbuf + oWm0, bm[0], o1b, 256);
  mlp_tail<<<M_MLP / 128, 256, 0, stream>>>(o1b, wbuf + oWm1, bm[1], wbuf + oWm2, bm[2],
                                            WmF[3], bm[3], out);
}

// Round 13
// 430.243 us; speedup vs baseline: 1.0504x; 1.0504x over previous
//
#include <hip/hip_runtime.h>
#include <hip/hip_bf16.h>
#include <math.h>

// Problem constants
#define N_NODES 30
#define E_BASE  82
#define E_TOT   112         // 82 edges + 30 self loops
#define B_GRAPH 1024
#define HID     256
#define NTOT    (B_GRAPH * N_NODES)   // 30720
#define MAXIN   32
#define N_EH    41
#define M_MLP   (B_GRAPH * N_EH)      // 41984

#define META_SRC  0
#define META_DST  E_TOT
#define META_CNT  (2 * E_TOT)
#define META_LIST 256
#define META_INTS 1216

typedef __attribute__((ext_vector_type(8))) short bf16x8;
typedef __attribute__((ext_vector_type(4))) short bf16x4;
typedef __attribute__((ext_vector_type(4))) float f32x4;
#define AS3 __attribute__((address_space(3)))
#define AS1 __attribute__((address_space(1)))

__device__ __forceinline__ void gload_lds16(const void* g, void* l) {
  __builtin_amdgcn_global_load_lds((const AS1 void*)g, (AS3 void*)l, 16, 0, 0);
}

// Bit-reinterpret ONLY — callers must pass raw bf16 bit patterns (short lanes
// of bf16x4/8 vectors). Never pass __hip_bfloat16 (would value-convert via
// float->short — the R3 NaN bug).
__device__ __forceinline__ float b2f(short s) {
  union { unsigned u; float f; } x;
  x.u = ((unsigned)(unsigned short)s) << 16;
  return x.f;
}

// ---------------------------------------------------------------------------
// Transpose-cast all weights fp32 [K,N] -> bf16 [N,K]; block 976 instead
// builds the base-graph CSR (merged to save a launch).
// ---------------------------------------------------------------------------
struct WtJob { const float* in; int K, N, tstart, ooff; };
struct WtArgs { WtJob j[10]; };

__global__ __launch_bounds__(256)
void transpose_weights(WtArgs args, __hip_bfloat16* __restrict__ out,
                       const int* __restrict__ ei, int* __restrict__ meta) {
  int b = blockIdx.x;
  if (b == 976) {   // build_graph job
    __shared__ int cnt[N_NODES];
    int tid = threadIdx.x;
    if (tid < N_NODES) cnt[tid] = 0;
    __syncthreads();
    if (tid < E_TOT) {
      int s, d;
      if (tid < E_BASE) { s = ei[tid]; d = ei[B_GRAPH * E_BASE + tid]; }
      else              { s = tid - E_BASE; d = s; }
      meta[META_SRC + tid] = s;
      meta[META_DST + tid] = d;
      int pos = atomicAdd(&cnt[d], 1);
      if (pos < MAXIN) meta[META_LIST + d * MAXIN + pos] = tid;
    }
    __syncthreads();
    if (tid < N_NODES) meta[META_CNT + tid] = cnt[tid];
    return;
  }
  int ji = 0;
  #pragma unroll
  for (int i = 1; i < 10; i++) if (b >= args.j[i].tstart) ji = i;
  WtJob jb = args.j[ji];
  int t = b - jb.tstart;
  int ntn = jb.N >> 5;
  int tk = t / ntn, tn = t - tk * ntn;
  int k0 = tk * 32, n0 = tn * 32;
  __shared__ float s[32][33];
  int tx = threadIdx.x & 31, ty = threadIdx.x >> 5;
  #pragma unroll
  for (int p = 0; p < 4; p++)
    s[ty + p * 8][tx] = jb.in[(size_t)(k0 + ty + p * 8) * jb.N + n0 + tx];
  __syncthreads();
  __hip_bfloat16* o = out + jb.ooff;
  #pragma unroll
  for (int p = 0; p < 4; p++) {
    int n = ty + p * 8;
    o[(size_t)(n0 + n) * jb.K + k0 + tx] = __float2bfloat16(s[tx][n]);
  }
}

// ---------------------------------------------------------------------------
// bf16 MFMA GEMM (R9 fragment/epilogue; BK=64 per R12 — two [128][32] sub-tiles
// per barrier pair, halves barrier-drain count; 53.2 -> 49.2 µs measured).
// C = act(A @ B + bias); A [M,K] bf16, Bt [N,K] bf16. K % 64 == 0.
// Split bias: col < N1 -> bias[col], else bias2[col-N1] (concat outputs).
// ---------------------------------------------------------------------------
template<int ACT, int OUTBF>
__global__ __launch_bounds__(256)
void gemm_mfma(const __hip_bfloat16* __restrict__ A, const __hip_bfloat16* __restrict__ Bt,
               const float* __restrict__ bias, const float* __restrict__ bias2,
               void* __restrict__ Cv, int M, int K, int N, int N1)
{
  __shared__ __hip_bfloat16 sA[2][128 * 32];
  __shared__ __hip_bfloat16 sB[2][128 * 32];
  const int tid = threadIdx.x;
  const int lane = tid & 63;
  const int wave = tid >> 6;
  const int wx = wave & 1, wy = wave >> 1;
  const int bm = blockIdx.x, bn = blockIdx.y;
  const int mrow = lane & 15, quad = lane >> 4;

  const int r0 = tid >> 2, kc0 = (tid & 3) * 8;
  const __hip_bfloat16* Ag0 = A + (size_t)(bm * 128 + r0) * K + kc0;
  const __hip_bfloat16* Ag1 = A + (size_t)(bm * 128 + r0 + 64) * K + kc0;
  const __hip_bfloat16* Bg0 = Bt + (size_t)(bn * 128 + r0) * K + kc0;
  const __hip_bfloat16* Bg1 = Bt + (size_t)(bn * 128 + r0 + 64) * K + kc0;

  f32x4 acc[4][4];
  #pragma unroll
  for (int i = 0; i < 4; i++)
    #pragma unroll
    for (int j = 0; j < 4; j++)
      acc[i][j] = (f32x4){0.f, 0.f, 0.f, 0.f};

  for (int kt = 0; kt < K; kt += 64) {
    __syncthreads();
    #pragma unroll
    for (int s = 0; s < 2; s++) {
      gload_lds16(Ag0 + kt + s * 32, &sA[s][tid * 8]);
      gload_lds16(Ag1 + kt + s * 32, &sA[s][2048 + tid * 8]);
      gload_lds16(Bg0 + kt + s * 32, &sB[s][tid * 8]);
      gload_lds16(Bg1 + kt + s * 32, &sB[s][2048 + tid * 8]);
    }
    __syncthreads();

    #pragma unroll
    for (int s = 0; s < 2; s++) {
      bf16x8 af[4], bfr[4];
      #pragma unroll
      for (int i = 0; i < 4; i++) {
        af[i]  = *(const bf16x8*)&sA[s][(wy * 64 + i * 16 + mrow) * 32 + quad * 8];
        bfr[i] = *(const bf16x8*)&sB[s][(wx * 64 + i * 16 + mrow) * 32 + quad * 8];
      }
      #pragma unroll
      for (int i = 0; i < 4; i++)
        #pragma unroll
        for (int j = 0; j < 4; j++)
          acc[i][j] = __builtin_amdgcn_mfma_f32_16x16x32_bf16(af[i], bfr[j], acc[i][j], 0, 0, 0);
    }
  }

  #pragma unroll
  for (int i = 0; i < 4; i++) {
    #pragma unroll
    for (int r = 0; r < 4; r++) {
      size_t row = (size_t)bm * 128 + wy * 64 + i * 16 + quad * 4 + r;
      #pragma unroll
      for (int j = 0; j < 4; j++) {
        int col = bn * 128 + wx * 64 + j * 16 + mrow;
        float bc = (col < N1) ? bias[col] : bias2[col - N1];
        float v = acc[i][j][r] + bc;
        if (ACT) v = v > 0.f ? v : 0.01f * v;
        if (OUTBF) ((__hip_bfloat16*)Cv)[row * N + col] = __float2bfloat16(v);
        else       ((float*)Cv)[row * N + col] = v;
      }
    }
  }
}

// ---------------------------------------------------------------------------
// MFMA GEMM with fp32 A staged via in-register bf16 cast (fused cast): proj.
// ---------------------------------------------------------------------------
template<int ACT, int OUTBF>
__global__ __launch_bounds__(256)
void gemm_mfma_f32a(const float* __restrict__ A, const __hip_bfloat16* __restrict__ Bt,
                    const float* __restrict__ bias, void* __restrict__ Cv,
                    int M, int K, int N)
{
  __shared__ __hip_bfloat16 sA[128 * 32];
  __shared__ __hip_bfloat16 sB[128 * 32];
  const int tid = threadIdx.x;
  const int lane = tid & 63;
  const int wave = tid >> 6;
  const int wx = wave & 1, wy = wave >> 1;
  const int bm = blockIdx.x, bn = blockIdx.y;
  const int mrow = lane & 15, quad = lane >> 4;

  const int r0 = tid >> 2, kc0 = (tid & 3) * 8;
  const float* Ag0 = A + (size_t)(bm * 128 + r0) * K + kc0;
  const float* Ag1 = A + (size_t)(bm * 128 + r0 + 64) * K + kc0;
  const __hip_bfloat16* Bg0 = Bt + (size_t)(bn * 128 + r0) * K + kc0;
  const __hip_bfloat16* Bg1 = Bt + (size_t)(bn * 128 + r0 + 64) * K + kc0;

  f32x4 acc[4][4];
  #pragma unroll
  for (int i = 0; i < 4; i++)
    #pragma unroll
    for (int j = 0; j < 4; j++)
      acc[i][j] = (f32x4){0.f, 0.f, 0.f, 0.f};

  for (int kt = 0; kt < K; kt += 32) {
    float4 a00 = *(const float4*)(Ag0 + kt);
    float4 a01 = *(const float4*)(Ag0 + kt + 4);
    float4 a10 = *(const float4*)(Ag1 + kt);
    float4 a11 = *(const float4*)(Ag1 + kt + 4);
    __syncthreads();
    {
      __hip_bfloat16 t[8];
      t[0] = __float2bfloat16(a00.x); t[1] = __float2bfloat16(a00.y);
      t[2] = __float2bfloat16(a00.z); t[3] = __float2bfloat16(a00.w);
      t[4] = __float2bfloat16(a01.x); t[5] = __float2bfloat16(a01.y);
      t[6] = __float2bfloat16(a01.z); t[7] = __float2bfloat16(a01.w);
      *(bf16x8*)&sA[tid * 8] = *(bf16x8*)t;
      t[0] = __float2bfloat16(a10.x); t[1] = __float2bfloat16(a10.y);
      t[2] = __float2bfloat16(a10.z); t[3] = __float2bfloat16(a10.w);
      t[4] = __float2bfloat16(a11.x); t[5] = __float2bfloat16(a11.y);
      t[6] = __float2bfloat16(a11.z); t[7] = __float2bfloat16(a11.w);
      *(bf16x8*)&sA[2048 + tid * 8] = *(bf16x8*)t;
    }
    gload_lds16(Bg0 + kt, &sB[tid * 8]);
    gload_lds16(Bg1 + kt, &sB[2048 + tid * 8]);
    __syncthreads();

    bf16x8 af[4], bfr[4];
    #pragma unroll
    for (int i = 0; i < 4; i++) {
      af[i]  = *(const bf16x8*)&sA[(wy * 64 + i * 16 + mrow) * 32 + quad * 8];
      bfr[i] = *(const bf16x8*)&sB[(wx * 64 + i * 16 + mrow) * 32 + quad * 8];
    }
    #pragma unroll
    for (int i = 0; i < 4; i++)
      #pragma unroll
      for (int j = 0; j < 4; j++)
        acc[i][j] = __builtin_amdgcn_mfma_f32_16x16x32_bf16(af[i], bfr[j], acc[i][j], 0, 0, 0);
  }

  #pragma unroll
  for (int i = 0; i < 4; i++) {
    #pragma unroll
    for (int r = 0; r < 4; r++) {
      size_t row = (size_t)bm * 128 + wy * 64 + i * 16 + quad * 4 + r;
      #pragma unroll
      for (int j = 0; j < 4; j++) {
        int col = bn * 128 + wx * 64 + j * 16 + mrow;
        float v = acc[i][j][r] + bias[col];
        if (ACT) v = v > 0.f ? v : 0.01f * v;
        if (OUTBF) ((__hip_bfloat16*)Cv)[row * N + col] = __float2bfloat16(v);
        else       ((float*)Cv)[row * N + col] = v;
      }
    }
  }
}

// ---------------------------------------------------------------------------
// MFMA GEMM with fused edge-pair gather from fp32 h:
// A-row r = concat(h[b,u], h[b,v]) with b=r/41, (u,v)=pairs[r%41]; K=512.
// C = lrelu(A @ Bt + bias), bf16 out.
// ---------------------------------------------------------------------------
__global__ __launch_bounds__(256)
void gemm_mfma_pair(const float* __restrict__ h, const int* __restrict__ pairs,
                    const __hip_bfloat16* __restrict__ Bt, const float* __restrict__ bias,
                    __hip_bfloat16* __restrict__ C, int N)
{
  const int K = 512;
  __shared__ __hip_bfloat16 sA[128 * 32];
  __shared__ __hip_bfloat16 sB[128 * 32];
  const int tid = threadIdx.x;
  const int lane = tid & 63;
  const int wave = tid >> 6;
  const int wx = wave & 1, wy = wave >> 1;
  const int bm = blockIdx.x, bn = blockIdx.y;
  const int mrow = lane & 15, quad = lane >> 4;

  const float* pu[2]; const float* pv[2]; int sub[2];
  #pragma unroll
  for (int cI = 0; cI < 2; cI++) {
    int c = tid + cI * 256;
    int r0 = c >> 2; sub[cI] = (c & 3) * 8;
    int R = bm * 128 + r0;
    int b = R / N_EH, p = R - b * N_EH;
    int u = pairs[p * 2], v = pairs[p * 2 + 1];
    pu[cI] = h + ((size_t)b * N_NODES + u) * HID;
    pv[cI] = h + ((size_t)b * N_NODES + v) * HID;
  }

  const int r0 = tid >> 2, kc0 = (tid & 3) * 8;
  const __hip_bfloat16* Bg0 = Bt + (size_t)(bn * 128 + r0) * K + kc0;
  const __hip_bfloat16* Bg1 = Bt + (size_t)(bn * 128 + r0 + 64) * K + kc0;

  f32x4 acc[4][4];
  #pragma unroll
  for (int i = 0; i < 4; i++)
    #pragma unroll
    for (int j = 0; j < 4; j++)
      acc[i][j] = (f32x4){0.f, 0.f, 0.f, 0.f};

  for (int kt = 0; kt < K; kt += 32) {
    float4 av[2][2];
    #pragma unroll
    for (int cI = 0; cI < 2; cI++) {
      const float* src = (kt < 256 ? pu[cI] + kt : pv[cI] + kt - 256) + sub[cI];
      av[cI][0] = *(const float4*)src;
      av[cI][1] = *(const float4*)(src + 4);
    }
    __syncthreads();
    #pragma unroll
    for (int cI = 0; cI < 2; cI++) {
      __hip_bfloat16 t[8];
      t[0] = __float2bfloat16(av[cI][0].x); t[1] = __float2bfloat16(av[cI][0].y);
      t[2] = __float2bfloat16(av[cI][0].z); t[3] = __float2bfloat16(av[cI][0].w);
      t[4] = __float2bfloat16(av[cI][1].x); t[5] = __float2bfloat16(av[cI][1].y);
      t[6] = __float2bfloat16(av[cI][1].z); t[7] = __float2bfloat16(av[cI][1].w);
      *(bf16x8*)&sA[(tid + cI * 256) * 8] = *(bf16x8*)t;
    }
    gload_lds16(Bg0 + kt, &sB[tid * 8]);
    gload_lds16(Bg1 + kt, &sB[2048 + tid * 8]);
    __syncthreads();

    bf16x8 af[4], bfr[4];
    #pragma unroll
    for (int i = 0; i < 4; i++) {
      af[i]  = *(const bf16x8*)&sA[(wy * 64 + i * 16 + mrow) * 32 + quad * 8];
      bfr[i] = *(const bf16x8*)&sB[(wx * 64 + i * 16 + mrow) * 32 + quad * 8];
    }
    #pragma unroll
    for (int i = 0; i < 4; i++)
      #pragma unroll
      for (int j = 0; j < 4; j++)
        acc[i][j] = __builtin_amdgcn_mfma_f32_16x16x32_bf16(af[i], bfr[j], acc[i][j], 0, 0, 0);
  }

  #pragma unroll
  for (int i = 0; i < 4; i++) {
    #pragma unroll
    for (int r = 0; r < 4; r++) {
      size_t row = (size_t)bm * 128 + wy * 64 + i * 16 + quad * 4 + r;
      #pragma unroll
      for (int j = 0; j < 4; j++) {
        int col = bn * 128 + wx * 64 + j * 16 + mrow;
        float v = acc[i][j][r] + bias[col];
        v = v > 0.f ? v : 0.01f * v;
        C[row * N + col] = __float2bfloat16(v);
      }
    }
  }
}

// ---------------------------------------------------------------------------
// Fused MLP tail (R11 — proven win).
// ---------------------------------------------------------------------------
#define O2P 136
__global__ __launch_bounds__(256)
void mlp_tail(const __hip_bfloat16* __restrict__ o1, const __hip_bfloat16* __restrict__ W1t,
              const float* __restrict__ b1, const __hip_bfloat16* __restrict__ W2t,
              const float* __restrict__ b2, const float* __restrict__ w3,
              const float* __restrict__ b3, float* __restrict__ out)
{
  __shared__ __hip_bfloat16 sA[128 * 32];
  __shared__ __hip_bfloat16 sB[128 * 32];
  __shared__ __hip_bfloat16 sO2[128 * O2P];
  __shared__ float spart[2][128];
  const int tid = threadIdx.x;
  const int lane = tid & 63;
  const int wave = tid >> 6;
  const int wx = wave & 1, wy = wave >> 1;
  const int bm = blockIdx.x;
  const int mrow = lane & 15, quad = lane >> 4;
  const int r0 = tid >> 2, kc0 = (tid & 3) * 8;

  const __hip_bfloat16* Ag0 = o1 + (size_t)(bm * 128 + r0) * 256 + kc0;
  const __hip_bfloat16* Ag1 = o1 + (size_t)(bm * 128 + r0 + 64) * 256 + kc0;
  const __hip_bfloat16* Bg0 = W1t + (size_t)r0 * 256 + kc0;
  const __hip_bfloat16* Bg1 = W1t + (size_t)(r0 + 64) * 256 + kc0;

  f32x4 acc[4][4];
  #pragma unroll
  for (int i = 0; i < 4; i++)
    #pragma unroll
    for (int j = 0; j < 4; j++)
      acc[i][j] = (f32x4){0.f, 0.f, 0.f, 0.f};

  for (int kt = 0; kt < 256; kt += 32) {
    __syncthreads();
    gload_lds16(Ag0 + kt, &sA[tid * 8]);
    gload_lds16(Ag1 + kt, &sA[2048 + tid * 8]);
    gload_lds16(Bg0 + kt, &sB[tid * 8]);
    gload_lds16(Bg1 + kt, &sB[2048 + tid * 8]);
    __syncthreads();

    bf16x8 af[4], bfr[4];
    #pragma unroll
    for (int i = 0; i < 4; i++) {
      af[i]  = *(const bf16x8*)&sA[(wy * 64 + i * 16 + mrow) * 32 + quad * 8];
      bfr[i] = *(const bf16x8*)&sB[(wx * 64 + i * 16 + mrow) * 32 + quad * 8];
    }
    #pragma unroll
    for (int i = 0; i < 4; i++)
      #pragma unroll
      for (int j = 0; j < 4; j++)
        acc[i][j] = __builtin_amdgcn_mfma_f32_16x16x32_bf16(af[i], bfr[j], acc[i][j], 0, 0, 0);
  }

  __syncthreads();
  #pragma unroll
  for (int i = 0; i < 4; i++) {
    #pragma unroll
    for (int r = 0; r < 4; r++) {
      int row = wy * 64 + i * 16 + quad * 4 + r;
      #pragma unroll
      for (int j = 0; j < 4; j++) {
        int col = wx * 64 + j * 16 + mrow;
        float v = acc[i][j][r] + b1[col];
        v = v > 0.f ? v : 0.01f * v;
        sO2[row * O2P + col] = __float2bfloat16(v);
      }
    }
  }

  f32x4 acc2[4][4];
  #pragma unroll
  for (int i = 0; i < 4; i++)
    #pragma unroll
    for (int j = 0; j < 4; j++)
      acc2[i][j] = (f32x4){0.f, 0.f, 0.f, 0.f};

  for (int kt = 0; kt < 128; kt += 32) {
    __syncthreads();
    gload_lds16(W2t + (size_t)r0 * 128 + kt + kc0, &sB[tid * 8]);
    gload_lds16(W2t + (size_t)(r0 + 64) * 128 + kt + kc0, &sB[2048 + tid * 8]);
    __syncthreads();

    bf16x8 af[4], bfr[4];
    #pragma unroll
    for (int i = 0; i < 4; i++) {
      af[i]  = *(const bf16x8*)&sO2[(wy * 64 + i * 16 + mrow) * O2P + kt + quad * 8];
      bfr[i] = *(const bf16x8*)&sB[(wx * 64 + i * 16 + mrow) * 32 + quad * 8];
    }
    #pragma unroll
    for (int i = 0; i < 4; i++)
      #pragma unroll
      for (int j = 0; j < 4; j++)
        acc2[i][j] = __builtin_amdgcn_mfma_f32_16x16x32_bf16(af[i], bfr[j], acc2[i][j], 0, 0, 0);
  }

  float w3v[4], b2v[4];
  #pragma unroll
  for (int j = 0; j < 4; j++) {
    int col = wx * 64 + j * 16 + mrow;
    w3v[j] = w3[col];
    b2v[j] = b2[col];
  }
  #pragma unroll
  for (int i = 0; i < 4; i++) {
    #pragma unroll
    for (int r = 0; r < 4; r++) {
      float s = 0.f;
      #pragma unroll
      for (int j = 0; j < 4; j++) {
        float v = acc2[i][j][r] + b2v[j];
        v = v > 0.f ? v : 0.01f * v;
        s += v * w3v[j];
      }
      #pragma unroll
      for (int off = 8; off; off >>= 1) s += __shfl_xor(s, off);
      if (mrow == 0) {
        int row = wy * 64 + i * 16 + quad * 4 + r;
        spart[wx][row] = s;
      }
    }
  }
  __syncthreads();
  if (tid < 128)
    out[(size_t)bm * 128 + tid] = spart[0][tid] + spart[1][tid] + b3[0];
}

// ---------------------------------------------------------------------------
// LayerNorm over HID=256; one wave per row; writes bf16. (Used once, after proj.)
// ---------------------------------------------------------------------------
__global__ __launch_bounds__(256)
void layernorm(const float* __restrict__ h, const float* __restrict__ g,
               const float* __restrict__ b, __hip_bfloat16* __restrict__ hn)
{
  const int wv = threadIdx.x >> 6, lane = threadIdx.x & 63;
  const size_t row = (size_t)blockIdx.x * 4 + wv;
  const float* hr = h + row * HID;
  float v[4];
  float sum = 0.f;
  #pragma unroll
  for (int j = 0; j < 4; j++) { v[j] = hr[lane + 64 * j]; sum += v[j]; }
  #pragma unroll
  for (int off = 32; off; off >>= 1) sum += __shfl_xor(sum, off);
  float mu = sum * (1.f / 256.f);
  float vs = 0.f;
  #pragma unroll
  for (int j = 0; j < 4; j++) { float d = v[j] - mu; vs += d * d; }
  #pragma unroll
  for (int off = 32; off; off >>= 1) vs += __shfl_xor(vs, off);
  float rs = rsqrtf(vs * (1.f / 256.f) + 1e-5f);
  __hip_bfloat16* outr = hn + row * HID;
  #pragma unroll
  for (int j = 0; j < 4; j++) {
    int c = lane + 64 * j;
    outr[c] = __float2bfloat16((v[j] - mu) * rs * g[c] + b[c]);
  }
}

// ---------------------------------------------------------------------------
// GATv2 attention coefficients: one block per (graph, head). (R9 config.)
// ---------------------------------------------------------------------------
__global__ __launch_bounds__(256)
void gat_alpha(const __hip_bfloat16* __restrict__ xcat,
               const float* __restrict__ att, float* __restrict__ alphaG,
               const int* __restrict__ meta, int H)
{
  __shared__ __hip_bfloat16 sxl[N_NODES * HID];   // 15 KB
  __shared__ __hip_bfloat16 sxr[N_NODES * HID];   // 15 KB
  __shared__ float slog[E_TOT];
  __shared__ float smax[N_NODES];
  __shared__ float sden[N_NODES];
  __shared__ int ssrc[E_TOT], sdst[E_TOT], scnt[N_NODES], slist[N_NODES * MAXIN];

  const int tid = threadIdx.x;
  const int g = blockIdx.x, hh = blockIdx.y;
  const size_t nodebase = (size_t)g * N_NODES;
  const int S = 2 * H * HID;

  {
    int i = tid;
    #pragma unroll
    for (int p = 0; p < 4; p++, i += 256) {
      if (i < N_NODES * HID / 8) {
        int node = i >> 5, c = (i & 31) * 8;
        const __hip_bfloat16* row = &xcat[(nodebase + node) * S + c];
        gload_lds16(row + hh * HID, &sxl[(size_t)i * 8]);
        gload_lds16(row + (H + hh) * HID, &sxr[(size_t)i * 8]);
      }
    }
  }

  if (tid < E_TOT) { ssrc[tid] = meta[META_SRC + tid]; sdst[tid] = meta[META_DST + tid]; }
  if (tid < N_NODES) { scnt[tid] = meta[META_CNT + tid]; sden[tid] = 0.f; }
  for (int i = tid; i < N_NODES * MAXIN; i += 256) slist[i] = meta[META_LIST + i];

  const int wv = tid >> 6, l32 = tid & 31, esub = (tid >> 5) & 1;
  const int c0 = l32 * 8;
  float attr[8];
  #pragma unroll
  for (int j = 0; j < 8; j++) attr[j] = att[hh * HID + c0 + j];
  __syncthreads();

  #pragma unroll
  for (int pass = 0; pass < 14; pass++) {
    int e = pass * 8 + wv * 2 + esub;
    bf16x8 a = *(const bf16x8*)&sxl[ssrc[e] * HID + c0];
    bf16x8 b = *(const bf16x8*)&sxr[sdst[e] * HID + c0];
    float sum = 0.f;
    #pragma unroll
    for (int j = 0; j < 8; j++) {
      float v = b2f(a[j]) + b2f(b[j]);
      v = v > 0.f ? v : 0.2f * v;
      sum += v * attr[j];
    }
    #pragma unroll
    for (int off = 16; off; off >>= 1) sum += __shfl_xor(sum, off);
    if (l32 == 0) slog[e] = sum;
  }
  __syncthreads();

  if (tid < N_NODES) {
    int cnt = scnt[tid];
    const int* lst = &slist[tid * MAXIN];
    float m = -1e30f;
    for (int i = 0; i < cnt; i++) m = fmaxf(m, slog[lst[i]]);
    smax[tid] = m;
  }
  __syncthreads();
  if (tid < E_TOT) {
    float ex = expf(slog[tid] - smax[sdst[tid]]);
    slog[tid] = ex;
    atomicAdd(&sden[sdst[tid]], ex);
  }
  __syncthreads();
  if (tid < E_TOT)
    alphaG[((size_t)g * H + hh) * E_TOT + tid] = slog[tid] / sden[sdst[tid]];
}

// ---------------------------------------------------------------------------
// GATv2 aggregation + h update (+ optional fused next-layer LayerNorm):
// R11 full-channel version — channel-split (R12) regressed: per-block
// meta/alpha overhead doubled and LN un-fusion added 2 launches.
// One block per graph; thread = (channel-quad c4, node-group ng).
// ---------------------------------------------------------------------------
template<int DO_LN>
__global__ __launch_bounds__(256, 4)
void gat_agg(const __hip_bfloat16* __restrict__ xcat, const float* __restrict__ alphaG,
             const float* __restrict__ bias, float* __restrict__ h,
             const float* __restrict__ lnG, const float* __restrict__ lnB,
             __hip_bfloat16* __restrict__ hn, const int* __restrict__ meta, int H)
{
  __shared__ __hip_bfloat16 sxl[2][N_NODES * HID];   // 2 x 15 KB, head double-buffer
  __shared__ float salpha[2][E_TOT];
  __shared__ int ssrc[E_TOT], scnt[N_NODES], slist[N_NODES * MAXIN];

  const int tid = threadIdx.x;
  const int g = blockIdx.x;
  const size_t nodebase = (size_t)g * N_NODES;
  const int S = 2 * H * HID;
  const int c4 = tid & 63;
  const int ng = tid >> 6;

  if (tid < E_TOT) ssrc[tid] = meta[META_SRC + tid];
  if (tid < N_NODES) scnt[tid] = meta[META_CNT + tid];
  for (int i = tid; i < N_NODES * MAXIN; i += 256) slist[i] = meta[META_LIST + i];

  float4 hres[8];
  #pragma unroll
  for (int ki = 0; ki < 8; ki++) {
    int k = ng + ki * 4;
    if (k < N_NODES) hres[ki] = *(const float4*)&h[(nodebase + k) * HID + c4 * 4];
  }

  {
    int i = tid;
    #pragma unroll
    for (int p = 0; p < 4; p++, i += 256) {
      if (i < N_NODES * HID / 8) {
        int node = i >> 5, c = (i & 31) * 8;
        gload_lds16(&xcat[(nodebase + node) * S + 0 * HID + c], &sxl[0][(size_t)i * 8]);
      }
    }
    if (tid < E_TOT) salpha[0][tid] = alphaG[((size_t)g * H + 0) * E_TOT + tid];
  }

  float acc[8][4];
  #pragma unroll
  for (int ki = 0; ki < 8; ki++)
    #pragma unroll
    for (int j = 0; j < 4; j++) acc[ki][j] = 0.f;

  for (int hh = 0; hh < H; hh++) {
    const int buf = hh & 1;
    __syncthreads();
    if (hh + 1 < H) {
      const int nb = buf ^ 1;
      int i = tid;
      #pragma unroll
      for (int p = 0; p < 4; p++, i += 256) {
        if (i < N_NODES * HID / 8) {
          int node = i >> 5, c = (i & 31) * 8;
          gload_lds16(&xcat[(nodebase + node) * S + (hh + 1) * HID + c], &sxl[nb][(size_t)i * 8]);
        }
      }
      if (tid < E_TOT) salpha[nb][tid] = alphaG[((size_t)g * H + hh + 1) * E_TOT + tid];
    }
    #pragma unroll
    for (int ki = 0; ki < 8; ki++) {
      int k = ng + ki * 4;
      if (k < N_NODES) {
        int cnt = scnt[k];
        const int* lst = &slist[k * MAXIN];
        for (int i = 0; i < cnt; i++) {
          int e = lst[i];                       // wave-uniform broadcast reads
          float al = salpha[buf][e];
          bf16x4 v = *(const bf16x4*)&sxl[buf][ssrc[e] * HID + c4 * 4];
          acc[ki][0] += al * b2f(v[0]);
          acc[ki][1] += al * b2f(v[1]);
          acc[ki][2] += al * b2f(v[2]);
          acc[ki][3] += al * b2f(v[3]);
        }
      }
    }
  }

  const float invH = 1.f / (float)H;
  const float4 bs = *(const float4*)&bias[c4 * 4];
  float4 gv, bv;
  if (DO_LN) {
    gv = *(const float4*)&lnG[c4 * 4];
    bv = *(const float4*)&lnB[c4 * 4];
  }
  #pragma unroll
  for (int ki = 0; ki < 8; ki++) {
    int k = ng + ki * 4;
    if (k < N_NODES) {
      float o0 = acc[ki][0] * invH + bs.x; o0 = o0 > 0.f ? o0 : 0.01f * o0; o0 += hres[ki].x;
      float o1 = acc[ki][1] * invH + bs.y; o1 = o1 > 0.f ? o1 : 0.01f * o1; o1 += hres[ki].y;
      float o2 = acc[ki][2] * invH + bs.z; o2 = o2 > 0.f ? o2 : 0.01f * o2; o2 += hres[ki].z;
      float o3 = acc[ki][3] * invH + bs.w; o3 = o3 > 0.f ? o3 : 0.01f * o3; o3 += hres[ki].w;
      float4 o4 = {o0, o1, o2, o3};
      *(float4*)&h[(nodebase + k) * HID + c4 * 4] = o4;
      if (DO_LN) {
        float sum = o0 + o1 + o2 + o3;
        #pragma unroll
        for (int off = 32; off; off >>= 1) sum += __shfl_xor(sum, off);
        float mu = sum * (1.f / 256.f);
        float d0 = o0 - mu, d1 = o1 - mu, d2 = o2 - mu, d3 = o3 - mu;
        float vs = d0 * d0 + d1 * d1 + d2 * d2 + d3 * d3;
        #pragma unroll
        for (int off = 32; off; off >>= 1) vs += __shfl_xor(vs, off);
        float rs = rsqrtf(vs * (1.f / 256.f) + 1e-5f);
        __hip_bfloat16 t[4];
        t[0] = __float2bfloat16(d0 * rs * gv.x + bv.x);
        t[1] = __float2bfloat16(d1 * rs * gv.y + bv.y);
        t[2] = __float2bfloat16(d2 * rs * gv.z + bv.z);
        t[3] = __float2bfloat16(d3 * rs * gv.w + bv.w);
        *(bf16x4*)&hn[(nodebase + k) * HID + c4 * 4] = *(bf16x4*)t;
      }
    }
  }
}

// ---------------------------------------------------------------------------
extern "C" void kernel_launch(void* const* d_in, const int* in_sizes, int n_in,
                              void* d_out, int out_size, void* d_ws, size_t ws_size,
                              hipStream_t stream) {
  const float* x     = (const float*)d_in[0];
  const int*   ei    = (const int*)d_in[1];
  const int*   pairs = (const int*)d_in[2];
  const float* bp    = (const float*)d_in[4];
  const float *lng[3], *lnb[3], *bl[3], *br[3], *att[3], *bias[3];
  const float *WlF[3], *WrF[3];
  for (int l = 0; l < 3; l++) {
    int base = 5 + l * 8;
    lng[l]  = (const float*)d_in[base + 0];
    lnb[l]  = (const float*)d_in[base + 1];
    WlF[l]  = (const float*)d_in[base + 2];
    bl[l]   = (const float*)d_in[base + 3];
    WrF[l]  = (const float*)d_in[base + 4];
    br[l]   = (const float*)d_in[base + 5];
    att[l]  = (const float*)d_in[base + 6];
    bias[l] = (const float*)d_in[base + 7];
  }
  const float* WmF[4] = {(const float*)d_in[29], (const float*)d_in[31],
                         (const float*)d_in[33], (const float*)d_in[35]};
  const float* bm[4] = {(const float*)d_in[30], (const float*)d_in[32],
                        (const float*)d_in[34], (const float*)d_in[36]};

  // workspace layout (float offsets)
  float* ws  = (float*)d_ws;
  float* h   = ws;                                           // [0, 7864320)
  __hip_bfloat16* hnb = (__hip_bfloat16*)(ws + 7864320);     // 3,932,160 bf
  __hip_bfloat16* xcat = (__hip_bfloat16*)(ws + 11796480);   // up to 47,185,920 bf
  float* alphaG = ws + 35389440;                             // 344,064 f
  __hip_bfloat16* wbuf = (__hip_bfloat16*)(ws + 35733504);   // 999,424 bf
  int*   meta = (int*)(ws + 36233216);
  __hip_bfloat16* o1b = (__hip_bfloat16*)xcat;               // 10,747,904 bf (xcat dead)
  float* out = (float*)d_out;

  // bf16 transposed weight offsets (Wl and Wr contiguous per layer -> one GEMM)
  const int oWp = 0, oWl0 = 32768, oWr0 = 229376, oWl1 = 425984, oWr1 = 557056;
  const int oWl2 = 688128, oWr2 = 753664, oWm0 = 819200, oWm1 = 950272, oWm2 = 983040;

  WtArgs wa;
  wa.j[0] = {(const float*)d_in[3], 128, 256,   0, oWp };
  wa.j[1] = {WlF[0],              256, 768,  32, oWl0};
  wa.j[2] = {WrF[0],              256, 768, 224, oWr0};
  wa.j[3] = {WlF[1],              256, 512, 416, oWl1};
  wa.j[4] = {WrF[1],              256, 512, 544, oWr1};
  wa.j[5] = {WlF[2],              256, 256, 672, oWl2};
  wa.j[6] = {WrF[2],              256, 256, 736, oWr2};
  wa.j[7] = {WmF[0],              512, 256, 800, oWm0};
  wa.j[8] = {WmF[1],              256, 128, 928, oWm1};
  wa.j[9] = {WmF[2],              128, 128, 960, oWm2};
  transpose_weights<<<977, 256, 0, stream>>>(wa, wbuf, ei, meta);  // block 976 = build_graph

  // h = x @ Wp + bp   (fp32 A staged with fused bf16 cast; fp32 out)
  gemm_mfma_f32a<0, 0><<<dim3(NTOT / 128, 2), 256, 0, stream>>>(x, wbuf + oWp, bp, h,
                                                                NTOT, 128, 256);

  layernorm<<<NTOT / 4, 256, 0, stream>>>(h, lng[0], lnb[0], hnb);

  const int Hs[3] = {3, 2, 1};
  const int oWl[3] = {oWl0, oWl1, oWl2};
  for (int l = 0; l < 3; l++) {
    int N = 2 * Hs[l] * HID;   // combined xl|xr output
    gemm_mfma<0, 1><<<dim3(NTOT / 128, N / 128), 256, 0, stream>>>(
        hnb, wbuf + oWl[l], bl[l], br[l], xcat, NTOT, HID, N, N / 2);
    gat_alpha<<<dim3(B_GRAPH, Hs[l]), 256, 0, stream>>>(xcat, att[l], alphaG, meta, Hs[l]);
    if (l < 2)
      gat_agg<1><<<B_GRAPH, 256, 0, stream>>>(xcat, alphaG, bias[l], h,
                                              lng[l + 1], lnb[l + 1], hnb, meta, Hs[l]);
    else
      gat_agg<0><<<B_GRAPH, 256, 0, stream>>>(xcat, alphaG, bias[l], h,
                                              nullptr, nullptr, nullptr, meta, Hs[l]);
  }

  gemm_mfma_pair<<<dim3(M_MLP / 128, 2), 256, 0, stream>>>(h, pairs, wbuf + oWm0, bm[0], o1b, 256);
  mlp_tail<<<M_MLP / 128, 256, 0, stream>>>(o1b, wbuf + oWm1, bm[1], wbuf + oWm2, bm[2],
                                            WmF[3], bm[3], out);
}